// Round 8
// baseline (8358.400 us; speedup 1.0000x reference)
//
#include <hip/hip_runtime.h>

// ============================================================================
// 2-layer GRU RNN, persistent cooperative kernel. B=64, S=512, I=512, H=1024.
// Round 14: revert to R8 JOINT lockstep barriers (desync variants R10/R13 both
//           cost +0.9GB FETCH / +1.3ms — empirical law: keep lockstep) and
//           shave the intra-phase critical path:
//  (A) split-drain ladder: vmcnt(4)/(2)/(0) between cloud issue and MFMA
//      groups — early MFMAs overlap the LLC return tail (vmcnt is in-order;
//      cloads occupy tail j's, so after vmcnt(k) all j<KW-k operands ready).
//  (B) direct owner publish: owner waves store their 16-col halves straight
//      from registers (2B sc0sc1 stores), drain, signal a 2-word LDS
//      mini-barrier; tid0 raises the flag. Removes 2 syncthreads + hst
//      staging per step; waves 2-7 enter hidden z-MFMAs one sync earlier.
//  - joint barriers exactly R8: iter-end 64-flag flB (both layers),
//    phase-B 32-flag flA (own layer); pure-spin wave-0 polls.
//  - kept: weight preloads before waits, sched_barrier(0) after data drains
//    (R7 NaN lesson), hidden z/candidate-x section, x(t+1) prefetch.
// ============================================================================

typedef _Float16 f16;
typedef f16  f16x8 __attribute__((ext_vector_type(8)));
typedef float f32x4 __attribute__((ext_vector_type(4)));
typedef unsigned long long u64;

#define NB   64
#define SEQ  512
#define IDIM 512
#define HDIM 1024
#define NBH  (NB*HDIM)          // 65536 elems per h snapshot

// workspace layout (bytes)
#define OFF_H0   0u             // f16 [2][64][1024] = 262144  (coherent mirror)
#define OFF_H1   262144u        // f16 [2][64][1024]
#define OFF_H0R  524288u        // f16 [64][1024]    = 131072  (h*r broadcast)
#define OFF_H1R  655360u        // f16 [64][1024]
#define OFF_FLA  786432u        // A flags: [g*2+layer][32] u32 = 1KB
#define OFF_FLB  787456u        // B flags: [g][64] u32 = 1KB (L0: 0-31, L1: 32-63)
#define OFF_W16  790528u        // f16 frag-order weights, L0 then L1
#define W16_L0_ELEMS 4718592u   // 3*1024*1536 (L1 starts here)

#define SMEM_BYTES 37888        // red 32K | zst 2K | mb 16B | hf 2K

#define MFMA16 __builtin_amdgcn_mfma_f32_16x16x32_f16

__device__ __forceinline__ float sigf(float x){ return 1.0f/(1.0f+__expf(-x)); }
__device__ __forceinline__ float tanh_fast(float x){ float e=__expf(2.0f*x); return 1.0f - 2.0f/(e+1.0f); }

// 16B coherent load: bypasses L1+L2, reads coherence point. NOT compiler
// vmcnt-tracked -> explicit s_waitcnt + sched_barrier before dependent MFMAs.
__device__ __forceinline__ f16x8 cload16(const f16* p){
  f16x8 r;
  asm volatile("global_load_dwordx4 %0, %1, off sc0 sc1" : "=v"(r) : "v"(p));
  return r;
}
// 2B coherent write-through store (owner-wave direct publish)
__device__ __forceinline__ void cstore2(f16* p, f16 v){
  union { f16 h; unsigned short u; } cv; cv.h = v;
  unsigned u32 = cv.u;
  asm volatile("global_store_short %0, %1, off sc0 sc1" :: "v"(p), "v"(u32) : "memory");
}

// x fp32 -> f16 fragment (plain cached loads; x is read-only)
__device__ __forceinline__ f16x8 load_x_frag(const float* p){
  f32x4 v0 = *(const f32x4*)p;
  f32x4 v1 = *(const f32x4*)(p+4);
  f16x8 r;
  r[0]=(f16)v0[0]; r[1]=(f16)v0[1]; r[2]=(f16)v0[2]; r[3]=(f16)v0[3];
  r[4]=(f16)v1[0]; r[5]=(f16)v1[1]; r[6]=(f16)v1[2]; r[7]=(f16)v1[3];
  return r;
}

// wave-scope poll (pure spin, R8 cadence): active lanes l<cnt watch f[l]>=tgt
__device__ __forceinline__ void poll_wave(const unsigned* f, int cnt, unsigned tgt){
  const int lane = (int)(threadIdx.x & 63);
  const unsigned* p = f + (lane < cnt ? lane : 0);
  unsigned v;
  do { v = __hip_atomic_load(p, __ATOMIC_RELAXED, __HIP_MEMORY_SCOPE_AGENT); }
  while (!__all((lane >= cnt) || (v >= tgt)));
}
// WG-wide wait: wave 0 polls, syncthreads releases all 8 waves (R8 shape).
__device__ __forceinline__ void wait_all(const unsigned* f, int cnt, unsigned tgt){
  if (threadIdx.x < 64) poll_wave(f, cnt, tgt);
  __syncthreads();
}

template<int LAYER>
__device__ void run_rnn(int g, int n32, const float* x,
    const float* brp, const float* bzp, const float* bcp,
    char* ws, char* smem,
    unsigned* flA, unsigned* flB, int slotB){
  constexpr int K   = (LAYER==0) ? 1536 : 2048;
  constexpr int NKS = K/32;          // 48 | 64 ksteps
  constexpr int KW  = NKS/8;         // 6 | 8 ksteps per wave (kg-split 8)
  constexpr int XKS = (LAYER==0) ? 16 : 32;   // ksteps fed by x (L0) / h0 (L1)
  const int tid  = threadIdx.x;
  const int lane = tid & 63;
  const int kg   = tid >> 6;         // wave index = k-group 0..7
  const int quad = lane >> 4;
  const int qo   = quad*8;
  const int m_base = g*16;
  const int n_base = n32*32;
  const int arow   = m_base + (lane & 15);

  f32x4* red = (f32x4*)smem;                 // [4][8][64] f32x4 = 32768 B
  float* zst = (float*)(smem + 32768);       // [16][32] f32 = 2048 B
  volatile int* mb = (volatile int*)(smem + 34816); // 4 ints: A(0,1) B(2,3)
  float* hf  = (float*)(smem + 35840);       // [16][32] f32 = 2048 B

  hf[tid & 511] = 0.f;                       // 512 threads, 512 elems
  if (tid < 4) mb[tid] = 0;
  __syncthreads();

  f16* h0m = (f16*)(ws + OFF_H0);
  f16* h1m = (f16*)(ws + OFF_H1);
  f16* hrbuf = (LAYER==0) ? (f16*)(ws + OFF_H0R) : (f16*)(ws + OFF_H1R);
  f16* hown  = (LAYER==0) ? h0m : h1m;
  const char* w16L = ws + OFF_W16 + (LAYER ? (size_t)W16_L0_ELEMS*2 : 0);

  // weight fragment base pointers: [gate][ntile][kstep][lane*16B], 1KB/kstep
  const size_t lo = (size_t)lane*16;
  const int nt0 = n32*2, nt1 = n32*2 + 1;
  const char* bR0 = w16L + ((size_t)((0*64 + nt0)*NKS + kg*KW))*1024 + lo;
  const char* bR1 = w16L + ((size_t)((0*64 + nt1)*NKS + kg*KW))*1024 + lo;
  const char* bZ0 = w16L + ((size_t)((1*64 + nt0)*NKS + kg*KW))*1024 + lo;
  const char* bZ1 = w16L + ((size_t)((1*64 + nt1)*NKS + kg*KW))*1024 + lo;
  const char* bC0 = w16L + ((size_t)((2*64 + nt0)*NKS + kg*KW))*1024 + lo;
  const char* bC1 = w16L + ((size_t)((2*64 + nt1)*NKS + kg*KW))*1024 + lo;

  // per-lane bias for this wave's owner role (ntile = kg&1)
  const int col_own = n_base + (kg & 1)*16 + (lane & 15);
  const float bRv = brp[col_own], bZv = bzp[col_own], bCv = bcp[col_own];

  unsigned lgA = 0, lgB = 0;
  f16x8 fa[KW];
  f16x8 xf[KW];                              // L0 only: x frags for current t

  if (LAYER==0){                             // prefetch x(t=0)
#pragma unroll
    for (int j=0;j<KW;++j){
      int ks = kg*KW + j;
      if (ks < XKS) xf[j] = load_x_frag(x + ((size_t)arow*SEQ + 0)*IDIM + ks*32 + qo);
    }
  }

  for (int iter = 0; iter <= SEQ; ++iter){
    const bool act  = (LAYER==0) ? (iter < SEQ) : (iter >= 1);
    const int  bufA = (iter & 1) ^ 1;

    f32x4 aC0{0,0,0,0}, aC1{0,0,0,0};        // candidate acc spans A-tail + B

    // ================= PHASE A : r gate =================
    if (act){
      f16x8 wA[KW], wB[KW];                  // R weights: issue before wait
#pragma unroll
      for (int j=0;j<KW;++j){
        wA[j] = *(const f16x8*)(bR0 + j*1024);
        wB[j] = *(const f16x8*)(bR1 + j*1024);
      }
      wait_all(flB, 64, lgB);                // JOINT: both layers' publishes
#pragma unroll
      for (int j=0;j<KW;++j){                // cloads occupy tail j's
        int ks = kg*KW + j;
        if (LAYER==0){
          if (ks >= XKS)
            fa[j] = cload16(h0m + (size_t)bufA*NBH + (size_t)arow*HDIM + (ks-16)*32 + qo);
        } else {
          if (ks < 32)
            fa[j] = cload16(h0m + (size_t)bufA*NBH + (size_t)arow*HDIM + ks*32 + qo);
          else
            fa[j] = cload16(h1m + (size_t)(iter&1)*NBH + (size_t)arow*HDIM + (ks-32)*32 + qo);
        }
      }
      f32x4 aR0{0,0,0,0}, aR1{0,0,0,0};
      // split-drain ladder: vmcnt in-order -> after vmcnt(k), all but the k
      // newest cloads returned; j<KW-k operands are safe.
      asm volatile("s_waitcnt vmcnt(4)" ::: "memory");
      __builtin_amdgcn_sched_barrier(0);
#pragma unroll
      for (int j=0;j<KW-4;++j){
        int ks = kg*KW + j;
        const f16x8 a = (LAYER==0 && ks < XKS) ? xf[j] : fa[j];
        aR0 = MFMA16(a, wA[j], aR0, 0,0,0);
        aR1 = MFMA16(a, wB[j], aR1, 0,0,0);
      }
      asm volatile("s_waitcnt vmcnt(2)" ::: "memory");
      __builtin_amdgcn_sched_barrier(0);
#pragma unroll
      for (int j=KW-4;j<KW-2;++j){
        int ks = kg*KW + j;
        const f16x8 a = (LAYER==0 && ks < XKS) ? xf[j] : fa[j];
        aR0 = MFMA16(a, wA[j], aR0, 0,0,0);
        aR1 = MFMA16(a, wB[j], aR1, 0,0,0);
      }
      asm volatile("s_waitcnt vmcnt(0)" ::: "memory");
      __builtin_amdgcn_sched_barrier(0);
#pragma unroll
      for (int j=KW-2;j<KW;++j){
        int ks = kg*KW + j;
        const f16x8 a = (LAYER==0 && ks < XKS) ? xf[j] : fa[j];
        aR0 = MFMA16(a, wA[j], aR0, 0,0,0);
        aR1 = MFMA16(a, wB[j], aR1, 0,0,0);
      }
      red[(0*8+kg)*64+lane] = aR0;
      red[(1*8+kg)*64+lane] = aR1;
    }
    __syncthreads();                         // red[0..1] ready
    ++lgA;
    if (act && kg < 2){                      // owner waves: r + DIRECT publish
      f32x4 s = red[(kg*8+0)*64+lane];
#pragma unroll
      for (int k2=1;k2<8;++k2) s += red[(kg*8+k2)*64+lane];
      const int coll = kg*16 + (lane & 15);
#pragma unroll
      for (int i=0;i<4;++i){
        int rowl = quad*4 + i;
        float r = sigf(s[i] + bRv);
        cstore2(hrbuf + (size_t)(m_base+rowl)*HDIM + n_base + coll,
                (f16)(hf[rowl*32 + coll] * r));
      }
      asm volatile("s_waitcnt vmcnt(0)" ::: "memory");
      if (lane == 0) mb[kg] = (int)iter + 1; // my half drained
    }
    if (tid == 0){                           // wave0: wait wave1, raise flag
      if (act) while (mb[1] < (int)iter + 1) {}
      __hip_atomic_store(flA + n32, lgA, __ATOMIC_RELAXED, __HIP_MEMORY_SCOPE_AGENT);
    }

    // ---- hidden under phase-B wait: z gate + candidate x-part ----
    if (act){
      f16x8 wA[KW], wB[KW];
#pragma unroll
      for (int j=0;j<KW;++j){
        wA[j] = *(const f16x8*)(bZ0 + j*1024);
        wB[j] = *(const f16x8*)(bZ1 + j*1024);
      }
      f32x4 aZ0{0,0,0,0}, aZ1{0,0,0,0};
#pragma unroll
      for (int j=0;j<KW;++j){
        int ks = kg*KW + j;
        const f16x8 a = (LAYER==0 && ks < XKS) ? xf[j] : fa[j];
        aZ0 = MFMA16(a, wA[j], aZ0, 0,0,0);
        aZ1 = MFMA16(a, wB[j], aZ1, 0,0,0);
      }
      red[(2*8+kg)*64+lane] = aZ0;
      red[(3*8+kg)*64+lane] = aZ1;
#pragma unroll
      for (int j=0;j<KW;++j){                // candidate x-part (held frags)
        int ks = kg*KW + j;
        if (ks < XKS){
          const f16x8 a = (LAYER==0) ? xf[j] : fa[j];
          aC0 = MFMA16(a, *(const f16x8*)(bC0 + j*1024), aC0, 0,0,0);
          aC1 = MFMA16(a, *(const f16x8*)(bC1 + j*1024), aC1, 0,0,0);
        }
      }
    }
    __syncthreads();                         // red[2..3] writes -> z-reduce
    if (act && (kg == 2 || kg == 3)){        // z reduce overlaps wave-0 poll
      f32x4 s = red[(kg*8+0)*64+lane];
#pragma unroll
      for (int k2=1;k2<8;++k2) s += red[(kg*8+k2)*64+lane];
      const int coll = (kg & 1)*16 + (lane & 15);
#pragma unroll
      for (int i=0;i<4;++i)
        zst[(quad*4+i)*32 + coll] = sigf(s[i] + bZv);
    }

    // ================= PHASE B : candidate h-part + h update =================
    if (act){
      f16x8 wA[KW], wB[KW];                  // C h-part weights before wait
#pragma unroll
      for (int j=0;j<KW;++j){
        int ks = kg*KW + j;
        if (ks >= XKS){
          wA[j] = *(const f16x8*)(bC0 + j*1024);
          wB[j] = *(const f16x8*)(bC1 + j*1024);
        }
      }
      wait_all(flA, 32, lgA);                // own-layer h*r producers
#pragma unroll
      for (int j=0;j<KW;++j){                // cloads occupy tail j's
        int ks = kg*KW + j;
        if (ks >= XKS)
          fa[j] = cload16(hrbuf + (size_t)arow*HDIM + (ks-XKS)*32 + qo);
      }
      asm volatile("s_waitcnt vmcnt(2)" ::: "memory");
      __builtin_amdgcn_sched_barrier(0);
#pragma unroll
      for (int j=0;j<KW-2;++j){
        int ks = kg*KW + j;
        if (ks >= XKS){
          aC0 = MFMA16(fa[j], wA[j], aC0, 0,0,0);
          aC1 = MFMA16(fa[j], wB[j], aC1, 0,0,0);
        }
      }
      asm volatile("s_waitcnt vmcnt(0)" ::: "memory");
      __builtin_amdgcn_sched_barrier(0);
#pragma unroll
      for (int j=KW-2;j<KW;++j){
        int ks = kg*KW + j;
        if (ks >= XKS){
          aC0 = MFMA16(fa[j], wA[j], aC0, 0,0,0);
          aC1 = MFMA16(fa[j], wB[j], aC1, 0,0,0);
        }
      }
      red[(0*8+kg)*64+lane] = aC0;
      red[(1*8+kg)*64+lane] = aC1;
    }
    __syncthreads();                         // red/zst writes -> h update
    ++lgB;
    if (act && kg < 2){                      // owners: h update + DIRECT publish
      f32x4 s = red[(kg*8+0)*64+lane];
#pragma unroll
      for (int k2=1;k2<8;++k2) s += red[(kg*8+k2)*64+lane];
      const int coll = kg*16 + (lane & 15);
      const int bufW = (LAYER==0) ? (iter&1) : ((iter&1)^1);
#pragma unroll
      for (int i=0;i<4;++i){
        int rowl = quad*4 + i;
        float can = tanh_fast(s[i] + bCv);
        float z   = zst[rowl*32 + coll];
        float hnew = hf[rowl*32 + coll]*z + (1.0f - z)*can;
        hf[rowl*32 + coll] = hnew;
        cstore2(hown + (size_t)bufW*NBH + (size_t)(m_base+rowl)*HDIM + n_base + coll,
                (f16)hnew);
      }
      asm volatile("s_waitcnt vmcnt(0)" ::: "memory");
      if (lane == 0) mb[2 + kg] = (int)iter + 1;
    }
    if (tid == 0){                           // wave0: wait wave1, raise flag
      if (act) while (mb[3] < (int)iter + 1) {}
      __hip_atomic_store(flB + slotB, lgB, __ATOMIC_RELAXED, __HIP_MEMORY_SCOPE_AGENT);
    }
    // ---- x(t+1) prefetch (L0), ahead of next round's wait ----
    if (LAYER==0 && iter+1 < SEQ){
#pragma unroll
      for (int j=0;j<KW;++j){
        int ks = kg*KW + j;
        if (ks < XKS)
          xf[j] = load_x_frag(x + ((size_t)arow*SEQ + (iter+1))*IDIM + ks*32 + qo);
      }
    }
  }
}

__global__ void __launch_bounds__(512, 2)
rnn_kernel(const float* x,
           const float* br0, const float* bz0, const float* bc0,
           const float* br1, const float* bz1, const float* bc1,
           const float* Wreg, const float* breg,
           float* out, char* ws){
  extern __shared__ char smem[];
  const int b = blockIdx.x;
  // XCD packing: same (layer,n32) pair's 4 batch-groups land on one XCD
  const int xcd = b & 7, slot = b >> 3;
  const int g = slot & 3, phi = slot >> 2;
  const int p = phi*8 + xcd;                  // 0..63 unique (layer, n32)
  const int layer = p >> 5, n32 = p & 31;
  unsigned* flA  = (unsigned*)(ws + OFF_FLA) + (g*2 + layer)*32;
  unsigned* flB  = (unsigned*)(ws + OFF_FLB) + g*64;
  const int slotB = layer*32 + n32;

  if (layer==0) run_rnn<0>(g, n32, x, br0,bz0,bc0, ws, smem, flA, flB, slotB);
  else          run_rnn<1>(g, n32, x, br1,bz1,bc1, ws, smem, flA, flB, slotB);

  // regressor: one L1 WG per group handles its 16 rows (h1 final in buf 1)
  if (layer==1 && n32==0 && threadIdx.x < 32){
    // all 32 L1 WGs of this group must have published their final h1 block
    poll_wave((unsigned*)(ws + OFF_FLB) + g*64 + 32, 32, SEQ + 1u);
    int mrow = g*16 + ((int)threadIdx.x >> 1), o = threadIdx.x & 1;
    const _Float16* hp = (const _Float16*)(ws + OFF_H1) + (size_t)NBH + (size_t)mrow*HDIM;
    const float* wp = Wreg + (size_t)o*HDIM;
    float acc = 0.f;
#pragma unroll 4
    for (int k=0;k<HDIM;k+=4){
      u64 q = __hip_atomic_load((const u64*)(hp+k), __ATOMIC_RELAXED, __HIP_MEMORY_SCOPE_AGENT);
      union { u64 qq; _Float16 h[4]; } u; u.qq = q;
      acc += (float)u.h[0]*wp[k]   + (float)u.h[1]*wp[k+1]
           + (float)u.h[2]*wp[k+2] + (float)u.h[3]*wp[k+3];
    }
    out[mrow*2 + o] = acc + breg[o];
  }
}

// weights fp32 row-major [n][k] -> fp16 MFMA-frag order
// [layer][gate][ntile(64)][kstep][lane(64)][e(8)]; dst flat index == thread id
__global__ void prep_w(const float* Wr0, const float* Wz0, const float* Wc0,
                       const float* Wr1, const float* Wz1, const float* Wc1,
                       f16* w16){
  size_t i = (size_t)blockIdx.x*256 + threadIdx.x;
  const bool l1 = (i >= (size_t)W16_L0_ELEMS);
  size_t j = l1 ? i - (size_t)W16_L0_ELEMS : i;
  const int K   = l1 ? 2048 : 1536;
  const int NKS = K >> 5;
  int e    = (int)(j & 7);
  int lane = (int)((j >> 3) & 63);
  size_t r = j >> 9;
  int ks   = (int)(r % (size_t)NKS);
  size_t gnt = r / (size_t)NKS;
  int nt   = (int)(gnt & 63);
  int gate = (int)(gnt >> 6);
  int n = nt*16 + (lane & 15);
  int k = ks*32 + ((lane >> 4) << 3) + e;
  const float* W = l1 ? (gate==0 ? Wr1 : gate==1 ? Wz1 : Wc1)
                      : (gate==0 ? Wr0 : gate==1 ? Wz0 : Wc0);
  w16[i] = (f16)W[(size_t)n*K + k];
}

extern "C" void kernel_launch(void* const* d_in, const int* in_sizes, int n_in,
                              void* d_out, int out_size, void* d_ws, size_t ws_size,
                              hipStream_t stream){
  const float* x    = (const float*)d_in[0];
  const float* Wr0  = (const float*)d_in[1];
  const float* br0  = (const float*)d_in[2];
  const float* Wz0  = (const float*)d_in[3];
  const float* bz0  = (const float*)d_in[4];
  const float* Wc0  = (const float*)d_in[5];
  const float* bc0  = (const float*)d_in[6];
  const float* Wr1  = (const float*)d_in[7];
  const float* br1  = (const float*)d_in[8];
  const float* Wz1  = (const float*)d_in[9];
  const float* bz1  = (const float*)d_in[10];
  const float* Wc1  = (const float*)d_in[11];
  const float* bc1  = (const float*)d_in[12];
  const float* Wreg = (const float*)d_in[13];
  const float* breg = (const float*)d_in[14];
  float* out = (float*)d_out;
  char*  ws  = (char*)d_ws;

  // zero h mirrors + h*r buffers + flag region
  hipMemsetAsync(ws, 0, OFF_W16, stream);

  // weights -> fp16 frag order (3*1024*1536 + 3*1024*2048 = 11010048 elems)
  prep_w<<<43008, 256, 0, stream>>>(Wr0, Wz0, Wc0, Wr1, Wz1, Wc1,
                                    (f16*)(ws + OFF_W16));

  hipFuncSetAttribute((const void*)rnn_kernel,
                      hipFuncAttributeMaxDynamicSharedMemorySize, 160*1024);

  void* args[] = { (void*)&x,
                   (void*)&br0, (void*)&bz0, (void*)&bc0,
                   (void*)&br1, (void*)&bz1, (void*)&bc1,
                   (void*)&Wreg, (void*)&breg,
                   (void*)&out, (void*)&ws };
  hipLaunchCooperativeKernel((const void*)rnn_kernel, dim3(256), dim3(512),
                             args, (unsigned)SMEM_BYTES, stream);
}

// Round 9
// 6560.172 us; speedup vs baseline: 1.2741x; 1.2741x over previous
//
#include <hip/hip_runtime.h>

// ============================================================================
// 2-layer GRU RNN, persistent cooperative kernel. B=64, S=512, I=512, H=1024.
// Round 15: R8 exchange format (staged LDS -> 64x16B coherent publish; the
//           only format that doesn't regress) + the single unindicted R14
//           component: weight-preload-before-wait + split-drain vmcnt ladder.
//           R14 post-mortem: 2B direct publish caused +1.4GB FETCH (partial-
//           sector coherent RMW) and the 2.6ms regression; ladder passed
//           refcheck and cannot raise FETCH -> isolate it this round.
//  - joint lockstep barriers exactly R8 (desync always loses: R10/R13).
//  - phase A: R-weights issue BEFORE wait_all (L2 latency hides under poll);
//    cloads after release in j-order; vmcnt(4)/(2)/(0) ladder so early MFMA
//    groups overlap the LLC return tail (cloads sit at tail j's; x-prefetch
//    loads are oldest; weights drained during the poll).
//  - phase B: C-weights before wait_all(flA); vmcnt(2)/(0) ladder.
//  - kept: sched_barrier(0) after every data drain (R7 NaN lesson), hidden
//    z/candidate-x section, x(t+1) prefetch, pure-spin wave-0 polls.
// ============================================================================

typedef _Float16 f16;
typedef f16  f16x8 __attribute__((ext_vector_type(8)));
typedef float f32x4 __attribute__((ext_vector_type(4)));
typedef unsigned long long u64;

#define NB   64
#define SEQ  512
#define IDIM 512
#define HDIM 1024
#define NBH  (NB*HDIM)          // 65536 elems per h snapshot

// workspace layout (bytes)
#define OFF_H0   0u             // f16 [2][64][1024] = 262144  (coherent mirror)
#define OFF_H1   262144u        // f16 [2][64][1024]
#define OFF_H0R  524288u        // f16 [64][1024]    = 131072  (h*r broadcast)
#define OFF_H1R  655360u        // f16 [64][1024]
#define OFF_FLA  786432u        // A flags: [g*2+layer][32] u32 = 1KB
#define OFF_FLB  787456u        // B flags: [g][64] u32 = 1KB (L0: 0-31, L1: 32-63)
#define OFF_W16  790528u        // f16 frag-order weights, L0 then L1
#define W16_L0_ELEMS 4718592u   // 3*1024*1536 (L1 starts here)

#define SMEM_BYTES 37888        // red 32K | zst 2K | hst 1K | hf 2K  (exact)

#define MFMA16 __builtin_amdgcn_mfma_f32_16x16x32_f16

__device__ __forceinline__ float sigf(float x){ return 1.0f/(1.0f+__expf(-x)); }
__device__ __forceinline__ float tanh_fast(float x){ float e=__expf(2.0f*x); return 1.0f - 2.0f/(e+1.0f); }

// 16B coherent load: bypasses L1+L2, reads coherence point. NOT compiler
// vmcnt-tracked -> explicit s_waitcnt + sched_barrier before dependent MFMAs.
__device__ __forceinline__ f16x8 cload16(const f16* p){
  f16x8 r;
  asm volatile("global_load_dwordx4 %0, %1, off sc0 sc1" : "=v"(r) : "v"(p));
  return r;
}
// 16B coherent write-through store (staged publish — the proven format)
__device__ __forceinline__ void cstore16(f16* p, f16x8 v){
  asm volatile("global_store_dwordx4 %0, %1, off sc0 sc1" :: "v"(p), "v"(v) : "memory");
}

// x fp32 -> f16 fragment (plain cached loads; x is read-only)
__device__ __forceinline__ f16x8 load_x_frag(const float* p){
  f32x4 v0 = *(const f32x4*)p;
  f32x4 v1 = *(const f32x4*)(p+4);
  f16x8 r;
  r[0]=(f16)v0[0]; r[1]=(f16)v0[1]; r[2]=(f16)v0[2]; r[3]=(f16)v0[3];
  r[4]=(f16)v1[0]; r[5]=(f16)v1[1]; r[6]=(f16)v1[2]; r[7]=(f16)v1[3];
  return r;
}

// wave-scope poll (pure spin, R8 cadence): active lanes l<cnt watch f[l]>=tgt
__device__ __forceinline__ void poll_wave(const unsigned* f, int cnt, unsigned tgt){
  const int lane = (int)(threadIdx.x & 63);
  const unsigned* p = f + (lane < cnt ? lane : 0);
  unsigned v;
  do { v = __hip_atomic_load(p, __ATOMIC_RELAXED, __HIP_MEMORY_SCOPE_AGENT); }
  while (!__all((lane >= cnt) || (v >= tgt)));
}
// WG-wide wait: wave 0 polls, syncthreads releases all 8 waves (R8 shape).
__device__ __forceinline__ void wait_all(const unsigned* f, int cnt, unsigned tgt){
  if (threadIdx.x < 64) poll_wave(f, cnt, tgt);
  __syncthreads();
}

template<int LAYER>
__device__ void run_rnn(int g, int n32, const float* x,
    const float* brp, const float* bzp, const float* bcp,
    char* ws, char* smem,
    unsigned* flA, unsigned* flB, int slotB){
  constexpr int K   = (LAYER==0) ? 1536 : 2048;
  constexpr int NKS = K/32;          // 48 | 64 ksteps
  constexpr int KW  = NKS/8;         // 6 | 8 ksteps per wave (kg-split 8)
  constexpr int XKS = (LAYER==0) ? 16 : 32;   // ksteps fed by x (L0) / h0 (L1)
  const int tid  = threadIdx.x;
  const int lane = tid & 63;
  const int kg   = tid >> 6;         // wave index = k-group 0..7
  const int quad = lane >> 4;
  const int qo   = quad*8;
  const int m_base = g*16;
  const int n_base = n32*32;
  const int arow   = m_base + (lane & 15);

  f32x4* red = (f32x4*)smem;                 // [4][8][64] f32x4 = 32768 B
  float* zst = (float*)(smem + 32768);       // [16][32] f32 = 2048 B
  f16*   hst = (f16*)  (smem + 34816);       // [16][32] f16 = 1024 B
  float* hf  = (float*)(smem + 35840);       // [16][32] f32 = 2048 B (ends 37888)

  hf[tid & 511] = 0.f;                       // 512 threads, 512 elems
  __syncthreads();

  f16* h0m = (f16*)(ws + OFF_H0);
  f16* h1m = (f16*)(ws + OFF_H1);
  f16* hrbuf = (LAYER==0) ? (f16*)(ws + OFF_H0R) : (f16*)(ws + OFF_H1R);
  f16* hown  = (LAYER==0) ? h0m : h1m;
  const char* w16L = ws + OFF_W16 + (LAYER ? (size_t)W16_L0_ELEMS*2 : 0);

  // weight fragment base pointers: [gate][ntile][kstep][lane*16B], 1KB/kstep
  const size_t lo = (size_t)lane*16;
  const int nt0 = n32*2, nt1 = n32*2 + 1;
  const char* bR0 = w16L + ((size_t)((0*64 + nt0)*NKS + kg*KW))*1024 + lo;
  const char* bR1 = w16L + ((size_t)((0*64 + nt1)*NKS + kg*KW))*1024 + lo;
  const char* bZ0 = w16L + ((size_t)((1*64 + nt0)*NKS + kg*KW))*1024 + lo;
  const char* bZ1 = w16L + ((size_t)((1*64 + nt1)*NKS + kg*KW))*1024 + lo;
  const char* bC0 = w16L + ((size_t)((2*64 + nt0)*NKS + kg*KW))*1024 + lo;
  const char* bC1 = w16L + ((size_t)((2*64 + nt1)*NKS + kg*KW))*1024 + lo;

  // per-lane bias for this wave's owner role (ntile = kg&1)
  const int col_own = n_base + (kg & 1)*16 + (lane & 15);
  const float bRv = brp[col_own], bZv = bzp[col_own], bCv = bcp[col_own];

  unsigned lgA = 0, lgB = 0;
  f16x8 fa[KW];
  f16x8 xf[KW];                              // L0 only: x frags for current t

  if (LAYER==0){                             // prefetch x(t=0)
#pragma unroll
    for (int j=0;j<KW;++j){
      int ks = kg*KW + j;
      if (ks < XKS) xf[j] = load_x_frag(x + ((size_t)arow*SEQ + 0)*IDIM + ks*32 + qo);
    }
  }

  for (int iter = 0; iter <= SEQ; ++iter){
    const bool act  = (LAYER==0) ? (iter < SEQ) : (iter >= 1);
    const int  bufA = (iter & 1) ^ 1;

    f32x4 aC0{0,0,0,0}, aC1{0,0,0,0};        // candidate acc spans A-tail + B

    // ================= PHASE A : r gate =================
    if (act){
      f16x8 wA[KW], wB[KW];                  // R weights: issue before wait
#pragma unroll
      for (int j=0;j<KW;++j){
        wA[j] = *(const f16x8*)(bR0 + j*1024);
        wB[j] = *(const f16x8*)(bR1 + j*1024);
      }
      wait_all(flB, 64, lgB);                // JOINT: both layers' publishes
#pragma unroll
      for (int j=0;j<KW;++j){                // cloads occupy tail j's
        int ks = kg*KW + j;
        if (LAYER==0){
          if (ks >= XKS)
            fa[j] = cload16(h0m + (size_t)bufA*NBH + (size_t)arow*HDIM + (ks-16)*32 + qo);
        } else {
          if (ks < 32)
            fa[j] = cload16(h0m + (size_t)bufA*NBH + (size_t)arow*HDIM + ks*32 + qo);
          else
            fa[j] = cload16(h1m + (size_t)(iter&1)*NBH + (size_t)arow*HDIM + (ks-32)*32 + qo);
        }
      }
      f32x4 aR0{0,0,0,0}, aR1{0,0,0,0};
      // split-drain ladder: vmcnt in-order -> after vmcnt(k), all but the k
      // newest loads returned; j<KW-k operands (issued earlier) are safe.
      asm volatile("s_waitcnt vmcnt(4)" ::: "memory");
      __builtin_amdgcn_sched_barrier(0);
#pragma unroll
      for (int j=0;j<KW-4;++j){
        int ks = kg*KW + j;
        const f16x8 a = (LAYER==0 && ks < XKS) ? xf[j] : fa[j];
        aR0 = MFMA16(a, wA[j], aR0, 0,0,0);
        aR1 = MFMA16(a, wB[j], aR1, 0,0,0);
      }
      asm volatile("s_waitcnt vmcnt(2)" ::: "memory");
      __builtin_amdgcn_sched_barrier(0);
#pragma unroll
      for (int j=KW-4;j<KW-2;++j){
        int ks = kg*KW + j;
        const f16x8 a = (LAYER==0 && ks < XKS) ? xf[j] : fa[j];
        aR0 = MFMA16(a, wA[j], aR0, 0,0,0);
        aR1 = MFMA16(a, wB[j], aR1, 0,0,0);
      }
      asm volatile("s_waitcnt vmcnt(0)" ::: "memory");
      __builtin_amdgcn_sched_barrier(0);
#pragma unroll
      for (int j=KW-2;j<KW;++j){
        int ks = kg*KW + j;
        const f16x8 a = (LAYER==0 && ks < XKS) ? xf[j] : fa[j];
        aR0 = MFMA16(a, wA[j], aR0, 0,0,0);
        aR1 = MFMA16(a, wB[j], aR1, 0,0,0);
      }
      red[(0*8+kg)*64+lane] = aR0;
      red[(1*8+kg)*64+lane] = aR1;
    }
    __syncthreads();
    if (act && kg < 2){                      // owner waves: (r, ntile kg)
      f32x4 s = red[(kg*8+0)*64+lane];
#pragma unroll
      for (int k2=1;k2<8;++k2) s += red[(kg*8+k2)*64+lane];
      const int coll = kg*16 + (lane & 15);
#pragma unroll
      for (int i=0;i<4;++i){
        int rowl = quad*4 + i;
        float r = sigf(s[i] + bRv);
        hst[rowl*32 + coll] = (f16)(hf[rowl*32 + coll] * r);
      }
    }
    __syncthreads();
    if (act && tid < 64){                    // publish h*r block (16B stores)
      int rowl = tid >> 2, c8 = (tid & 3)*8;
      f16x8 v = *(const f16x8*)(hst + rowl*32 + c8);
      cstore16(hrbuf + (size_t)(m_base+rowl)*HDIM + n_base + c8, v);
    }
    // arrive A (publisher wave drains its own stores, then tid0 raises flag)
    asm volatile("s_waitcnt vmcnt(0) lgkmcnt(0)" ::: "memory");
    ++lgA;
    if (tid == 0)
      __hip_atomic_store(flA + n32, lgA, __ATOMIC_RELAXED, __HIP_MEMORY_SCOPE_AGENT);

    // ---- hidden under phase-B wait: z gate + candidate x-part ----
    if (act){
      f16x8 wA[KW], wB[KW];
#pragma unroll
      for (int j=0;j<KW;++j){
        wA[j] = *(const f16x8*)(bZ0 + j*1024);
        wB[j] = *(const f16x8*)(bZ1 + j*1024);
      }
      f32x4 aZ0{0,0,0,0}, aZ1{0,0,0,0};
#pragma unroll
      for (int j=0;j<KW;++j){
        int ks = kg*KW + j;
        const f16x8 a = (LAYER==0 && ks < XKS) ? xf[j] : fa[j];
        aZ0 = MFMA16(a, wA[j], aZ0, 0,0,0);
        aZ1 = MFMA16(a, wB[j], aZ1, 0,0,0);
      }
      red[(2*8+kg)*64+lane] = aZ0;
      red[(3*8+kg)*64+lane] = aZ1;
#pragma unroll
      for (int j=0;j<KW;++j){                // candidate x-part (held frags)
        int ks = kg*KW + j;
        if (ks < XKS){
          const f16x8 a = (LAYER==0) ? xf[j] : fa[j];
          aC0 = MFMA16(a, *(const f16x8*)(bC0 + j*1024), aC0, 0,0,0);
          aC1 = MFMA16(a, *(const f16x8*)(bC1 + j*1024), aC1, 0,0,0);
        }
      }
    }
    __syncthreads();                         // red[2..3] writes -> z-reduce
    if (act && (kg == 2 || kg == 3)){        // z reduce overlaps wave-0 poll
      f32x4 s = red[(kg*8+0)*64+lane];
#pragma unroll
      for (int k2=1;k2<8;++k2) s += red[(kg*8+k2)*64+lane];
      const int coll = (kg & 1)*16 + (lane & 15);
#pragma unroll
      for (int i=0;i<4;++i)
        zst[(quad*4+i)*32 + coll] = sigf(s[i] + bZv);
    }

    // ================= PHASE B : candidate h-part + h update =================
    if (act){
      f16x8 wA[KW], wB[KW];                  // C h-part weights before wait
#pragma unroll
      for (int j=0;j<KW;++j){
        int ks = kg*KW + j;
        if (ks >= XKS){
          wA[j] = *(const f16x8*)(bC0 + j*1024);
          wB[j] = *(const f16x8*)(bC1 + j*1024);
        }
      }
      wait_all(flA, 32, lgA);                // own-layer h*r producers
#pragma unroll
      for (int j=0;j<KW;++j){                // cloads occupy tail j's
        int ks = kg*KW + j;
        if (ks >= XKS)
          fa[j] = cload16(hrbuf + (size_t)arow*HDIM + (ks-XKS)*32 + qo);
      }
      asm volatile("s_waitcnt vmcnt(2)" ::: "memory");
      __builtin_amdgcn_sched_barrier(0);
#pragma unroll
      for (int j=0;j<KW-2;++j){
        int ks = kg*KW + j;
        if (ks >= XKS){
          aC0 = MFMA16(fa[j], wA[j], aC0, 0,0,0);
          aC1 = MFMA16(fa[j], wB[j], aC1, 0,0,0);
        }
      }
      asm volatile("s_waitcnt vmcnt(0)" ::: "memory");
      __builtin_amdgcn_sched_barrier(0);
#pragma unroll
      for (int j=KW-2;j<KW;++j){
        int ks = kg*KW + j;
        if (ks >= XKS){
          aC0 = MFMA16(fa[j], wA[j], aC0, 0,0,0);
          aC1 = MFMA16(fa[j], wB[j], aC1, 0,0,0);
        }
      }
      red[(0*8+kg)*64+lane] = aC0;
      red[(1*8+kg)*64+lane] = aC1;
    }
    __syncthreads();                         // red/zst writes -> h update
    if (act && kg < 2){                      // owner waves: ntile = kg
      f32x4 s = red[(kg*8+0)*64+lane];
#pragma unroll
      for (int k2=1;k2<8;++k2) s += red[(kg*8+k2)*64+lane];
      const int coll = kg*16 + (lane & 15);
#pragma unroll
      for (int i=0;i<4;++i){
        int rowl = quad*4 + i;
        float can = tanh_fast(s[i] + bCv);
        float z   = zst[rowl*32 + coll];
        float hnew = hf[rowl*32 + coll]*z + (1.0f - z)*can;
        hf[rowl*32 + coll]  = hnew;
        hst[rowl*32 + coll] = (f16)hnew;
      }
    }
    __syncthreads();                         // hst writes -> publish
    if (act && tid < 64){                    // publish h block (16B stores)
      const int bufW = (LAYER==0) ? (iter&1) : ((iter&1)^1);
      int rowl = tid >> 2, c8 = (tid & 3)*8;
      f16x8 v = *(const f16x8*)(hst + rowl*32 + c8);
      cstore16(hown + (size_t)bufW*NBH + (size_t)(m_base+rowl)*HDIM + n_base + c8, v);
    }
    // arrive B
    asm volatile("s_waitcnt vmcnt(0) lgkmcnt(0)" ::: "memory");
    ++lgB;
    if (tid == 0)
      __hip_atomic_store(flB + slotB, lgB, __ATOMIC_RELAXED, __HIP_MEMORY_SCOPE_AGENT);
    // ---- x(t+1) prefetch (L0), ahead of next round's wait ----
    if (LAYER==0 && iter+1 < SEQ){
#pragma unroll
      for (int j=0;j<KW;++j){
        int ks = kg*KW + j;
        if (ks < XKS)
          xf[j] = load_x_frag(x + ((size_t)arow*SEQ + (iter+1))*IDIM + ks*32 + qo);
      }
    }
  }
}

__global__ void __launch_bounds__(512, 2)
rnn_kernel(const float* x,
           const float* br0, const float* bz0, const float* bc0,
           const float* br1, const float* bz1, const float* bc1,
           const float* Wreg, const float* breg,
           float* out, char* ws){
  extern __shared__ char smem[];
  const int b = blockIdx.x;
  // XCD packing: same (layer,n32) pair's 4 batch-groups land on one XCD
  const int xcd = b & 7, slot = b >> 3;
  const int g = slot & 3, phi = slot >> 2;
  const int p = phi*8 + xcd;                  // 0..63 unique (layer, n32)
  const int layer = p >> 5, n32 = p & 31;
  unsigned* flA  = (unsigned*)(ws + OFF_FLA) + (g*2 + layer)*32;
  unsigned* flB  = (unsigned*)(ws + OFF_FLB) + g*64;
  const int slotB = layer*32 + n32;

  if (layer==0) run_rnn<0>(g, n32, x, br0,bz0,bc0, ws, smem, flA, flB, slotB);
  else          run_rnn<1>(g, n32, x, br1,bz1,bc1, ws, smem, flA, flB, slotB);

  // regressor: one L1 WG per group handles its 16 rows (h1 final in buf 1)
  if (layer==1 && n32==0 && threadIdx.x < 32){
    // all 32 L1 WGs of this group must have published their final h1 block
    poll_wave((unsigned*)(ws + OFF_FLB) + g*64 + 32, 32, SEQ + 1u);
    int mrow = g*16 + ((int)threadIdx.x >> 1), o = threadIdx.x & 1;
    const _Float16* hp = (const _Float16*)(ws + OFF_H1) + (size_t)NBH + (size_t)mrow*HDIM;
    const float* wp = Wreg + (size_t)o*HDIM;
    float acc = 0.f;
#pragma unroll 4
    for (int k=0;k<HDIM;k+=4){
      u64 q = __hip_atomic_load((const u64*)(hp+k), __ATOMIC_RELAXED, __HIP_MEMORY_SCOPE_AGENT);
      union { u64 qq; _Float16 h[4]; } u; u.qq = q;
      acc += (float)u.h[0]*wp[k]   + (float)u.h[1]*wp[k+1]
           + (float)u.h[2]*wp[k+2] + (float)u.h[3]*wp[k+3];
    }
    out[mrow*2 + o] = acc + breg[o];
  }
}

// weights fp32 row-major [n][k] -> fp16 MFMA-frag order
// [layer][gate][ntile(64)][kstep][lane(64)][e(8)]; dst flat index == thread id
__global__ void prep_w(const float* Wr0, const float* Wz0, const float* Wc0,
                       const float* Wr1, const float* Wz1, const float* Wc1,
                       f16* w16){
  size_t i = (size_t)blockIdx.x*256 + threadIdx.x;
  const bool l1 = (i >= (size_t)W16_L0_ELEMS);
  size_t j = l1 ? i - (size_t)W16_L0_ELEMS : i;
  const int K   = l1 ? 2048 : 1536;
  const int NKS = K >> 5;
  int e    = (int)(j & 7);
  int lane = (int)((j >> 3) & 63);
  size_t r = j >> 9;
  int ks   = (int)(r % (size_t)NKS);
  size_t gnt = r / (size_t)NKS;
  int nt   = (int)(gnt & 63);
  int gate = (int)(gnt >> 6);
  int n = nt*16 + (lane & 15);
  int k = ks*32 + ((lane >> 4) << 3) + e;
  const float* W = l1 ? (gate==0 ? Wr1 : gate==1 ? Wz1 : Wc1)
                      : (gate==0 ? Wr0 : gate==1 ? Wz0 : Wc0);
  w16[i] = (f16)W[(size_t)n*K + k];
}

extern "C" void kernel_launch(void* const* d_in, const int* in_sizes, int n_in,
                              void* d_out, int out_size, void* d_ws, size_t ws_size,
                              hipStream_t stream){
  const float* x    = (const float*)d_in[0];
  const float* Wr0  = (const float*)d_in[1];
  const float* br0  = (const float*)d_in[2];
  const float* Wz0  = (const float*)d_in[3];
  const float* bz0  = (const float*)d_in[4];
  const float* Wc0  = (const float*)d_in[5];
  const float* bc0  = (const float*)d_in[6];
  const float* Wr1  = (const float*)d_in[7];
  const float* br1  = (const float*)d_in[8];
  const float* Wz1  = (const float*)d_in[9];
  const float* bz1  = (const float*)d_in[10];
  const float* Wc1  = (const float*)d_in[11];
  const float* bc1  = (const float*)d_in[12];
  const float* Wreg = (const float*)d_in[13];
  const float* breg = (const float*)d_in[14];
  float* out = (float*)d_out;
  char*  ws  = (char*)d_ws;

  // zero h mirrors + h*r buffers + flag region
  hipMemsetAsync(ws, 0, OFF_W16, stream);

  // weights -> fp16 frag order (3*1024*1536 + 3*1024*2048 = 11010048 elems)
  prep_w<<<43008, 256, 0, stream>>>(Wr0, Wz0, Wc0, Wr1, Wz1, Wc1,
                                    (f16*)(ws + OFF_W16));

  hipFuncSetAttribute((const void*)rnn_kernel,
                      hipFuncAttributeMaxDynamicSharedMemorySize, 160*1024);

  void* args[] = { (void*)&x,
                   (void*)&br0, (void*)&bz0, (void*)&bc0,
                   (void*)&br1, (void*)&bz1, (void*)&bc1,
                   (void*)&Wreg, (void*)&breg,
                   (void*)&out, (void*)&ws };
  hipLaunchCooperativeKernel((const void*)rnn_kernel, dim3(256), dim3(512),
                             args, (unsigned)SMEM_BYTES, stream);
}

// Round 10
// 5748.241 us; speedup vs baseline: 1.4541x; 1.1412x over previous
//
#include <hip/hip_runtime.h>

// ============================================================================
// 2-layer GRU RNN, persistent cooperative kernel. B=64, S=512, I=512, H=1024.
// Round 16: CHAMPION REVERT == Round 8 byte-for-byte (measured 5765 us).
// Session evidence: every structural deviation regressed —
//   R10/R13 desync (+1.3ms, +0.9GB FETCH), R14 2B publish (+2.6ms, +1.4GB),
//   R14/R15 vmcnt split-drain ladder (+0.8ms, +0.7GB each), R10 multi-wave
//   polls (+1.3ms). The machine is latency-floor-bound at ~11.2us/step over
//   1026 producer->consumer rounds; this structure is the measured optimum.
//  - distributed flag barriers (relaxed store + lane-parallel poll);
//    barrier A intra-layer (32 WG), barrier B joint (64 WG).
//  - Z-gate GEMM + candidate x-part MFMAs hidden under barrier-A wait.
//  - x(t+1) prefetched between arrive-B and wait-B (L0).
//  - weight fragments preloaded BEFORE the vmcnt(0) drains (overlap with
//    coherent h loads) — safe via sched_barrier(0) fences (R7 NaN lesson).
// ============================================================================

typedef _Float16 f16;
typedef f16  f16x8 __attribute__((ext_vector_type(8)));
typedef float f32x4 __attribute__((ext_vector_type(4)));
typedef unsigned long long u64;

#define NB   64
#define SEQ  512
#define IDIM 512
#define HDIM 1024
#define NBH  (NB*HDIM)          // 65536 elems per h snapshot

// workspace layout (bytes)
#define OFF_H0   0u             // f16 [2][64][1024] = 262144  (coherent mirror)
#define OFF_H1   262144u        // f16 [2][64][1024]
#define OFF_H0R  524288u        // f16 [64][1024]    = 131072  (h*r broadcast)
#define OFF_H1R  655360u        // f16 [64][1024]
#define OFF_FLA  786432u        // A flags: [g*2+layer][32] u32 = 1KB
#define OFF_FLB  787456u        // B flags: [g][64] u32 = 1KB
#define OFF_W16  790528u        // f16 frag-order weights, L0 then L1
#define W16_L0_ELEMS 4718592u   // 3*1024*1536 (L1 starts here)

#define SMEM_BYTES 37888        // red 32K | zst 2K | hst 1K | hf 2K  (exact)

#define MFMA16 __builtin_amdgcn_mfma_f32_16x16x32_f16

__device__ __forceinline__ float sigf(float x){ return 1.0f/(1.0f+__expf(-x)); }
__device__ __forceinline__ float tanh_fast(float x){ float e=__expf(2.0f*x); return 1.0f - 2.0f/(e+1.0f); }

// 16B coherent load: bypasses L1+L2, reads coherence point. NOT compiler
// vmcnt-tracked -> batch loads then one explicit s_waitcnt vmcnt(0) +
// sched_barrier(0).
__device__ __forceinline__ f16x8 cload16(const f16* p){
  f16x8 r;
  asm volatile("global_load_dwordx4 %0, %1, off sc0 sc1" : "=v"(r) : "v"(p));
  return r;
}
// 16B coherent write-through store
__device__ __forceinline__ void cstore16(f16* p, f16x8 v){
  asm volatile("global_store_dwordx4 %0, %1, off sc0 sc1" :: "v"(p), "v"(v) : "memory");
}

// x fp32 -> f16 fragment (plain cached loads; x is read-only)
__device__ __forceinline__ f16x8 load_x_frag(const float* p){
  f32x4 v0 = *(const f32x4*)p;
  f32x4 v1 = *(const f32x4*)(p+4);
  f16x8 r;
  r[0]=(f16)v0[0]; r[1]=(f16)v0[1]; r[2]=(f16)v0[2]; r[3]=(f16)v0[3];
  r[4]=(f16)v1[0]; r[5]=(f16)v1[1]; r[6]=(f16)v1[2]; r[7]=(f16)v1[3];
  return r;
}

template<int LAYER>
__device__ void run_rnn(int g, int n32, const float* x,
    const float* brp, const float* bzp, const float* bcp,
    char* ws, char* smem, unsigned* flA, unsigned* flB, int slotB){
  constexpr int K   = (LAYER==0) ? 1536 : 2048;
  constexpr int NKS = K/32;          // 48 | 64 ksteps
  constexpr int KW  = NKS/8;         // 6 | 8 ksteps per wave (kg-split 8)
  constexpr int XKS = (LAYER==0) ? 16 : 32;   // ksteps fed by x (L0) / h0 (L1)
  const int tid  = threadIdx.x;
  const int lane = tid & 63;
  const int kg   = tid >> 6;         // wave index = k-group 0..7
  const int quad = lane >> 4;
  const int qo   = quad*8;
  const int m_base = g*16;
  const int n_base = n32*32;
  const int arow   = m_base + (lane & 15);

  f32x4* red = (f32x4*)smem;                 // [4][8][64] f32x4 = 32768 B
  float* zst = (float*)(smem + 32768);       // [16][32] f32 = 2048 B
  f16*   hst = (f16*)  (smem + 34816);       // [16][32] f16 = 1024 B
  float* hf  = (float*)(smem + 35840);       // [16][32] f32 = 2048 B (ends 37888)

  hf[tid & 511] = 0.f;                       // 512 threads, 512 elems
  __syncthreads();

  f16* h0m = (f16*)(ws + OFF_H0);
  f16* h1m = (f16*)(ws + OFF_H1);
  f16* hrbuf = (LAYER==0) ? (f16*)(ws + OFF_H0R) : (f16*)(ws + OFF_H1R);
  f16* hown  = (LAYER==0) ? h0m : h1m;
  const char* w16L = ws + OFF_W16 + (LAYER ? (size_t)W16_L0_ELEMS*2 : 0);

  // weight fragment base pointers: [gate][ntile][kstep][lane*16B], 1KB/kstep
  const size_t lo = (size_t)lane*16;
  const int nt0 = n32*2, nt1 = n32*2 + 1;
  const char* bR0 = w16L + ((size_t)((0*64 + nt0)*NKS + kg*KW))*1024 + lo;
  const char* bR1 = w16L + ((size_t)((0*64 + nt1)*NKS + kg*KW))*1024 + lo;
  const char* bZ0 = w16L + ((size_t)((1*64 + nt0)*NKS + kg*KW))*1024 + lo;
  const char* bZ1 = w16L + ((size_t)((1*64 + nt1)*NKS + kg*KW))*1024 + lo;
  const char* bC0 = w16L + ((size_t)((2*64 + nt0)*NKS + kg*KW))*1024 + lo;
  const char* bC1 = w16L + ((size_t)((2*64 + nt1)*NKS + kg*KW))*1024 + lo;

  // per-lane bias for this wave's owner role (ntile = kg&1)
  const int col_own = n_base + (kg & 1)*16 + (lane & 15);
  const float bRv = brp[col_own], bZv = bzp[col_own], bCv = bcp[col_own];

  unsigned lgA = 0, lgB = 0;
  f16x8 fa[KW];
  f16x8 xf[KW];                              // L0 only: x frags for current t

  if (LAYER==0){                             // prefetch x(t=0)
#pragma unroll
    for (int j=0;j<KW;++j){
      int ks = kg*KW + j;
      if (ks < XKS) xf[j] = load_x_frag(x + ((size_t)arow*SEQ + 0)*IDIM + ks*32 + qo);
    }
  }

  for (int iter = 0; iter <= SEQ; ++iter){
    const bool act  = (LAYER==0) ? (iter < SEQ) : (iter >= 1);
    const int  bufA = (iter & 1) ^ 1;

    f32x4 aC0{0,0,0,0}, aC1{0,0,0,0};        // candidate acc spans A-tail + B

    // ================= PHASE A : r gate =================
    if (act){
#pragma unroll
      for (int j=0;j<KW;++j){
        int ks = kg*KW + j;
        if (LAYER==0){
          if (ks >= XKS)
            fa[j] = cload16(h0m + (size_t)bufA*NBH + (size_t)arow*HDIM + (ks-16)*32 + qo);
        } else {
          if (ks < 32)
            fa[j] = cload16(h0m + (size_t)bufA*NBH + (size_t)arow*HDIM + ks*32 + qo);
          else
            fa[j] = cload16(h1m + (size_t)(iter&1)*NBH + (size_t)arow*HDIM + (ks-32)*32 + qo);
        }
      }
      f16x8 wA[KW], wB[KW];                  // R weights overlap the cloads
#pragma unroll
      for (int j=0;j<KW;++j){
        wA[j] = *(const f16x8*)(bR0 + j*1024);
        wB[j] = *(const f16x8*)(bR1 + j*1024);
      }
      asm volatile("s_waitcnt vmcnt(0)" ::: "memory");
      __builtin_amdgcn_sched_barrier(0);     // pin MFMAs below the drain
      f32x4 aR0{0,0,0,0}, aR1{0,0,0,0};
#pragma unroll
      for (int j=0;j<KW;++j){
        int ks = kg*KW + j;
        const f16x8 a = (LAYER==0 && ks < XKS) ? xf[j] : fa[j];
        aR0 = MFMA16(a, wA[j], aR0, 0,0,0);
        aR1 = MFMA16(a, wB[j], aR1, 0,0,0);
      }
      red[(0*8+kg)*64+lane] = aR0;
      red[(1*8+kg)*64+lane] = aR1;
    }
    __syncthreads();
    if (act && kg < 2){                      // owner waves: (r, ntile kg)
      f32x4 s = red[(kg*8+0)*64+lane];
#pragma unroll
      for (int k2=1;k2<8;++k2) s += red[(kg*8+k2)*64+lane];
      const int coll = kg*16 + (lane & 15);
#pragma unroll
      for (int i=0;i<4;++i){
        int rowl = quad*4 + i;
        float r = sigf(s[i] + bRv);
        hst[rowl*32 + coll] = (f16)(hf[rowl*32 + coll] * r);
      }
    }
    __syncthreads();
    if (act && tid < 64){                    // publish h*r block (16B stores)
      int rowl = tid >> 2, c8 = (tid & 3)*8;
      f16x8 v = *(const f16x8*)(hst + rowl*32 + c8);
      cstore16(hrbuf + (size_t)(m_base+rowl)*HDIM + n_base + c8, v);
    }
    // arrive A (publisher wave drains its own stores, then tid0 raises flag)
    asm volatile("s_waitcnt vmcnt(0) lgkmcnt(0)" ::: "memory");
    ++lgA;
    if (tid == 0)
      __hip_atomic_store(flA + n32, lgA, __ATOMIC_RELAXED, __HIP_MEMORY_SCOPE_AGENT);

    // ---- hidden under barrier-A wait: z gate + candidate x-part ----
    if (act){
      f16x8 wA[KW], wB[KW];
#pragma unroll
      for (int j=0;j<KW;++j){
        wA[j] = *(const f16x8*)(bZ0 + j*1024);
        wB[j] = *(const f16x8*)(bZ1 + j*1024);
      }
      f32x4 aZ0{0,0,0,0}, aZ1{0,0,0,0};
#pragma unroll
      for (int j=0;j<KW;++j){
        int ks = kg*KW + j;
        const f16x8 a = (LAYER==0 && ks < XKS) ? xf[j] : fa[j];
        aZ0 = MFMA16(a, wA[j], aZ0, 0,0,0);
        aZ1 = MFMA16(a, wB[j], aZ1, 0,0,0);
      }
      red[(2*8+kg)*64+lane] = aZ0;
      red[(3*8+kg)*64+lane] = aZ1;
#pragma unroll
      for (int j=0;j<KW;++j){                // candidate x-part (held frags)
        int ks = kg*KW + j;
        if (ks < XKS){
          const f16x8 a = (LAYER==0) ? xf[j] : fa[j];
          aC0 = MFMA16(a, *(const f16x8*)(bC0 + j*1024), aC0, 0,0,0);
          aC1 = MFMA16(a, *(const f16x8*)(bC1 + j*1024), aC1, 0,0,0);
        }
      }
    }
    __syncthreads();
    if (act && (kg == 2 || kg == 3)){        // z reduce overlaps wave-0 poll
      f32x4 s = red[(kg*8+0)*64+lane];
#pragma unroll
      for (int k2=1;k2<8;++k2) s += red[(kg*8+k2)*64+lane];
      const int coll = (kg & 1)*16 + (lane & 15);
#pragma unroll
      for (int i=0;i<4;++i)
        zst[(quad*4+i)*32 + coll] = sigf(s[i] + bZv);
    }
    if (tid < 32){                           // wait A: intra-layer, 32 flags
      while (__hip_atomic_load(flA + tid, __ATOMIC_RELAXED, __HIP_MEMORY_SCOPE_AGENT) < lgA) {}
    }
    __syncthreads();

    // ================= PHASE B : candidate h-part + h update =================
    if (act && (kg+1)*KW > XKS){             // only waves with h*r ksteps
#pragma unroll
      for (int j=0;j<KW;++j){
        int ks = kg*KW + j;
        if (ks >= XKS)
          fa[j] = cload16(hrbuf + (size_t)arow*HDIM + (ks-XKS)*32 + qo);
      }
      f16x8 wA[KW], wB[KW];
#pragma unroll
      for (int j=0;j<KW;++j){
        int ks = kg*KW + j;
        if (ks >= XKS){
          wA[j] = *(const f16x8*)(bC0 + j*1024);
          wB[j] = *(const f16x8*)(bC1 + j*1024);
        }
      }
      asm volatile("s_waitcnt vmcnt(0)" ::: "memory");
      __builtin_amdgcn_sched_barrier(0);     // pin MFMAs below the drain
#pragma unroll
      for (int j=0;j<KW;++j){
        int ks = kg*KW + j;
        if (ks >= XKS){
          aC0 = MFMA16(fa[j], wA[j], aC0, 0,0,0);
          aC1 = MFMA16(fa[j], wB[j], aC1, 0,0,0);
        }
      }
    }
    if (act){
      red[(0*8+kg)*64+lane] = aC0;
      red[(1*8+kg)*64+lane] = aC1;
    }
    __syncthreads();
    if (act && kg < 2){                      // owner waves: ntile = kg
      f32x4 s = red[(kg*8+0)*64+lane];
#pragma unroll
      for (int k2=1;k2<8;++k2) s += red[(kg*8+k2)*64+lane];
      const int coll = kg*16 + (lane & 15);
#pragma unroll
      for (int i=0;i<4;++i){
        int rowl = quad*4 + i;
        float can = tanh_fast(s[i] + bCv);
        float z   = zst[rowl*32 + coll];
        float hnew = hf[rowl*32 + coll]*z + (1.0f - z)*can;
        hf[rowl*32 + coll]  = hnew;
        hst[rowl*32 + coll] = (f16)hnew;
      }
    }
    __syncthreads();
    if (act && tid < 64){                    // publish h block (16B stores)
      const int bufW = (LAYER==0) ? (iter&1) : ((iter&1)^1);
      int rowl = tid >> 2, c8 = (tid & 3)*8;
      f16x8 v = *(const f16x8*)(hst + rowl*32 + c8);
      cstore16(hown + (size_t)bufW*NBH + (size_t)(m_base+rowl)*HDIM + n_base + c8, v);
    }
    // arrive B
    asm volatile("s_waitcnt vmcnt(0) lgkmcnt(0)" ::: "memory");
    ++lgB;
    if (tid == 0)
      __hip_atomic_store(flB + slotB, lgB, __ATOMIC_RELAXED, __HIP_MEMORY_SCOPE_AGENT);
    // ---- hidden under barrier-B wait: x(t+1) prefetch (L0) ----
    if (LAYER==0 && iter+1 < SEQ){
#pragma unroll
      for (int j=0;j<KW;++j){
        int ks = kg*KW + j;
        if (ks < XKS)
          xf[j] = load_x_frag(x + ((size_t)arow*SEQ + (iter+1))*IDIM + ks*32 + qo);
      }
    }
    if (tid < 64){                           // wait B: joint layers, 64 flags
      while (__hip_atomic_load(flB + tid, __ATOMIC_RELAXED, __HIP_MEMORY_SCOPE_AGENT) < lgB) {}
    }
    __syncthreads();
  }
}

__global__ void __launch_bounds__(512, 2)
rnn_kernel(const float* x,
           const float* br0, const float* bz0, const float* bc0,
           const float* br1, const float* bz1, const float* bc1,
           const float* Wreg, const float* breg,
           float* out, char* ws){
  extern __shared__ char smem[];
  const int b = blockIdx.x;
  // XCD packing: same (layer,n32) pair's 4 batch-groups land on one XCD
  const int xcd = b & 7, slot = b >> 3;
  const int g = slot & 3, phi = slot >> 2;
  const int p = phi*8 + xcd;                  // 0..63 unique (layer, n32)
  const int layer = p >> 5, n32 = p & 31;
  unsigned* flA = (unsigned*)(ws + OFF_FLA) + (g*2 + layer)*32;
  unsigned* flB = (unsigned*)(ws + OFF_FLB) + g*64;
  const int slotB = layer*32 + n32;

  if (layer==0) run_rnn<0>(g, n32, x, br0,bz0,bc0, ws, smem, flA, flB, slotB);
  else          run_rnn<1>(g, n32, x, br1,bz1,bc1, ws, smem, flA, flB, slotB);

  // regressor: one L1 WG per group handles its 16 rows (h1 final in buf 1)
  if (layer==1 && n32==0 && threadIdx.x < 32){
    int mrow = g*16 + ((int)threadIdx.x >> 1), o = threadIdx.x & 1;
    const _Float16* hp = (const _Float16*)(ws + OFF_H1) + (size_t)NBH + (size_t)mrow*HDIM;
    const float* wp = Wreg + (size_t)o*HDIM;
    float acc = 0.f;
#pragma unroll 4
    for (int k=0;k<HDIM;k+=4){
      u64 q = __hip_atomic_load((const u64*)(hp+k), __ATOMIC_RELAXED, __HIP_MEMORY_SCOPE_AGENT);
      union { u64 qq; _Float16 h[4]; } u; u.qq = q;
      acc += (float)u.h[0]*wp[k]   + (float)u.h[1]*wp[k+1]
           + (float)u.h[2]*wp[k+2] + (float)u.h[3]*wp[k+3];
    }
    out[mrow*2 + o] = acc + breg[o];
  }
}

// weights fp32 row-major [n][k] -> fp16 MFMA-frag order
// [layer][gate][ntile(64)][kstep][lane(64)][e(8)]; dst flat index == thread id
__global__ void prep_w(const float* Wr0, const float* Wz0, const float* Wc0,
                       const float* Wr1, const float* Wz1, const float* Wc1,
                       f16* w16){
  size_t i = (size_t)blockIdx.x*256 + threadIdx.x;
  const bool l1 = (i >= (size_t)W16_L0_ELEMS);
  size_t j = l1 ? i - (size_t)W16_L0_ELEMS : i;
  const int K   = l1 ? 2048 : 1536;
  const int NKS = K >> 5;
  int e    = (int)(j & 7);
  int lane = (int)((j >> 3) & 63);
  size_t r = j >> 9;
  int ks   = (int)(r % (size_t)NKS);
  size_t gnt = r / (size_t)NKS;
  int nt   = (int)(gnt & 63);
  int gate = (int)(gnt >> 6);
  int n = nt*16 + (lane & 15);
  int k = ks*32 + ((lane >> 4) << 3) + e;
  const float* W = l1 ? (gate==0 ? Wr1 : gate==1 ? Wz1 : Wc1)
                      : (gate==0 ? Wr0 : gate==1 ? Wz0 : Wc0);
  w16[i] = (f16)W[(size_t)n*K + k];
}

extern "C" void kernel_launch(void* const* d_in, const int* in_sizes, int n_in,
                              void* d_out, int out_size, void* d_ws, size_t ws_size,
                              hipStream_t stream){
  const float* x    = (const float*)d_in[0];
  const float* Wr0  = (const float*)d_in[1];
  const float* br0  = (const float*)d_in[2];
  const float* Wz0  = (const float*)d_in[3];
  const float* bz0  = (const float*)d_in[4];
  const float* Wc0  = (const float*)d_in[5];
  const float* bc0  = (const float*)d_in[6];
  const float* Wr1  = (const float*)d_in[7];
  const float* br1  = (const float*)d_in[8];
  const float* Wz1  = (const float*)d_in[9];
  const float* bz1  = (const float*)d_in[10];
  const float* Wc1  = (const float*)d_in[11];
  const float* bc1  = (const float*)d_in[12];
  const float* Wreg = (const float*)d_in[13];
  const float* breg = (const float*)d_in[14];
  float* out = (float*)d_out;
  char*  ws  = (char*)d_ws;

  // zero h mirrors + h*r buffers + flag region
  hipMemsetAsync(ws, 0, OFF_W16, stream);

  // weights -> fp16 frag order (3*1024*1536 + 3*1024*2048 = 11010048 elems)
  prep_w<<<43008, 256, 0, stream>>>(Wr0, Wz0, Wc0, Wr1, Wz1, Wc1,
                                    (f16*)(ws + OFF_W16));

  hipFuncSetAttribute((const void*)rnn_kernel,
                      hipFuncAttributeMaxDynamicSharedMemorySize, 160*1024);

  void* args[] = { (void*)&x,
                   (void*)&br0, (void*)&bz0, (void*)&bc0,
                   (void*)&br1, (void*)&bz1, (void*)&bc1,
                   (void*)&Wreg, (void*)&breg,
                   (void*)&out, (void*)&ws };
  hipLaunchCooperativeKernel((const void*)rnn_kernel, dim3(256), dim3(512),
                             args, (unsigned)SMEM_BYTES, stream);
}